// Round 1
// baseline (418.833 us; speedup 1.0000x reference)
//
#include <hip/hip_runtime.h>

#define EMBED   256
#define NGRAPH  256
#define K1_CHUNK 512

// ---------------------------------------------------------------------------
// K1: segment sums of x into sums[256][256], exploiting sorted batch.
// Block handles K1_CHUNK consecutive nodes. Wave w processes nodes
// i ≡ w (mod 4); 64 lanes × float4 cover the 256-wide embedding (1 KB
// coalesced per node). Per-thread accumulator flushed via atomicAdd only
// when the graph id changes (wave-uniform branch).
// ---------------------------------------------------------------------------
__global__ __launch_bounds__(256) void seg_sum_kernel(
    const float* __restrict__ x, const int* __restrict__ batch,
    float* __restrict__ sums, int nNodes) {
  __shared__ int sb[K1_CHUNK];
  const int start = blockIdx.x * K1_CHUNK;
  const int cnt = min(K1_CHUNK, nNodes - start);
  for (int i = threadIdx.x; i < cnt; i += 256) sb[i] = batch[start + i];
  __syncthreads();

  const int q = threadIdx.x >> 6;        // node phase 0..3
  const int c = (threadIdx.x & 63) << 2; // column (float4 granularity)
  float4 acc = make_float4(0.f, 0.f, 0.f, 0.f);
  int cur = -1;
  for (int i = q; i < cnt; i += 4) {
    const int g = sb[i];  // broadcast within wave (all 64 lanes same i)
    const float4 v = *(const float4*)(x + (size_t)(start + i) * EMBED + c);
    if (g != cur) {       // wave-uniform, rare (~1-2 per block)
      if (cur >= 0) {
        float* p = sums + (size_t)cur * EMBED + c;
        atomicAdd(p + 0, acc.x); atomicAdd(p + 1, acc.y);
        atomicAdd(p + 2, acc.z); atomicAdd(p + 3, acc.w);
      }
      acc = make_float4(0.f, 0.f, 0.f, 0.f);
      cur = g;
    }
    acc.x += v.x; acc.y += v.y; acc.z += v.z; acc.w += v.w;
  }
  if (cur >= 0) {
    float* p = sums + (size_t)cur * EMBED + c;
    atomicAdd(p + 0, acc.x); atomicAdd(p + 1, acc.y);
    atomicAdd(p + 2, acc.z); atomicAdd(p + 3, acc.w);
  }
}

// ---------------------------------------------------------------------------
// K2: per-graph mean (count via binary search on sorted batch — no atomics),
// then out_graph = ((g @ Wv^T + bv) @ W2^T + b2). One block per graph,
// thread t owns output column t. Weight rows read as float4 (per-thread
// sequential -> 16x L1 line reuse; whole working set is 512 KB, L2-hot).
// ---------------------------------------------------------------------------
__global__ __launch_bounds__(256) void mlp_kernel(
    const float* __restrict__ sums, const int* __restrict__ batch,
    const float* __restrict__ in_w, const float* __restrict__ in_b,
    const float* __restrict__ out_w, const float* __restrict__ out_b,
    float* __restrict__ out_graph, int nNodes) {
  const int g = blockIdx.x;
  const int t = threadIdx.x;

  // first index with batch[m] >= g
  int lo = 0, hi = nNodes;
  while (lo < hi) { int m = (lo + hi) >> 1; (batch[m] <  g) ? (lo = m + 1) : (hi = m); }
  // first index with batch[m] > g
  int lo2 = lo, hi2 = nNodes;
  while (lo2 < hi2) { int m = (lo2 + hi2) >> 1; (batch[m] <= g) ? (lo2 = m + 1) : (hi2 = m); }
  const float inv = 1.0f / fmaxf((float)(lo2 - lo), 1.0f);

  __shared__ float sg[EMBED];
  __shared__ float sv[EMBED];
  sg[t] = sums[(size_t)g * EMBED + t] * inv;
  __syncthreads();

  const float* Wv = in_w + 2 * EMBED * EMBED;  // value projection rows
  float acc = in_b[2 * EMBED + t];
  const float4* wrow = (const float4*)(Wv + (size_t)t * EMBED);
#pragma unroll 8
  for (int k4 = 0; k4 < EMBED / 4; ++k4) {
    const float4 w = wrow[k4];
    const int k = k4 * 4;
    acc += sg[k] * w.x + sg[k + 1] * w.y + sg[k + 2] * w.z + sg[k + 3] * w.w;
  }
  sv[t] = acc;
  __syncthreads();

  float acc2 = out_b[t];
  const float4* w2row = (const float4*)(out_w + (size_t)t * EMBED);
#pragma unroll 8
  for (int k4 = 0; k4 < EMBED / 4; ++k4) {
    const float4 w = w2row[k4];
    const int k = k4 * 4;
    acc2 += sv[k] * w.x + sv[k + 1] * w.y + sv[k + 2] * w.z + sv[k + 3] * w.w;
  }
  out_graph[(size_t)g * EMBED + t] = acc2;
}

// ---------------------------------------------------------------------------
// K3: out[n] = out_graph[batch[n]] — 204.8 MB coalesced float4 stores;
// out_graph (256 KB) is L2/L1 resident; batch load is wave-uniform.
// ---------------------------------------------------------------------------
__global__ __launch_bounds__(256) void gather_kernel(
    const float* __restrict__ out_graph, const int* __restrict__ batch,
    float4* __restrict__ out, int nNodes) {
  const int i = blockIdx.x * 256 + threadIdx.x;
  const int total = nNodes * (EMBED / 4);
  if (i >= total) return;
  const int n = i >> 6;      // node
  const int c = i & 63;      // float4 column
  const int g = batch[n];    // uniform across the 64 float4s of a node
  out[i] = ((const float4*)out_graph)[g * (EMBED / 4) + c];
}

extern "C" void kernel_launch(void* const* d_in, const int* in_sizes, int n_in,
                              void* d_out, int out_size, void* d_ws, size_t ws_size,
                              hipStream_t stream) {
  const float* x     = (const float*)d_in[0];
  const float* in_w  = (const float*)d_in[1];
  const float* in_b  = (const float*)d_in[2];
  const float* out_w = (const float*)d_in[3];
  const float* out_b = (const float*)d_in[4];
  const int*   batch = (const int*)d_in[5];
  const int nNodes = in_sizes[5];

  float* sums      = (float*)d_ws;                  // [NGRAPH][EMBED]
  float* out_graph = sums + (size_t)NGRAPH * EMBED; // [NGRAPH][EMBED]

  hipMemsetAsync(sums, 0, (size_t)NGRAPH * EMBED * sizeof(float), stream);

  const int nb1 = (nNodes + K1_CHUNK - 1) / K1_CHUNK;
  seg_sum_kernel<<<nb1, 256, 0, stream>>>(x, batch, sums, nNodes);

  mlp_kernel<<<NGRAPH, 256, 0, stream>>>(sums, batch, in_w, in_b, out_w, out_b,
                                         out_graph, nNodes);

  const int nb3 = (nNodes * (EMBED / 4) + 255) / 256;
  gather_kernel<<<nb3, 256, 0, stream>>>(out_graph, batch, (float4*)d_out, nNodes);
}

// Round 2
// 403.730 us; speedup vs baseline: 1.0374x; 1.0374x over previous
//
#include <hip/hip_runtime.h>

#define EMBED   256
#define NGRAPH  256
#define K1_CHUNK 128   // 128 nodes/block -> 1563 blocks -> ~6 waves/SIMD

// ---------------------------------------------------------------------------
// K1: segment sums of x into sums[256][256], exploiting sorted batch.
// Block handles K1_CHUNK consecutive nodes; wave q processes nodes i≡q (mod 4);
// 64 lanes x float4 cover the 256-wide embedding (1 KB coalesced per node).
// FAST PATH (~84% of blocks): whole chunk belongs to ONE graph -> branch-free
// unrolled accumulate (8 independent loads in flight), single atomic flush.
// SLOW PATH (boundary blocks): per-node graph check, flush on change.
// ---------------------------------------------------------------------------
__global__ __launch_bounds__(256) void seg_sum_kernel(
    const float* __restrict__ x, const int* __restrict__ batch,
    float* __restrict__ sums, int nNodes) {
  __shared__ int sb[K1_CHUNK];
  const int start = blockIdx.x * K1_CHUNK;
  const int cnt = min(K1_CHUNK, nNodes - start);
  if (threadIdx.x < cnt) sb[threadIdx.x] = batch[start + threadIdx.x];
  __syncthreads();

  const int q = threadIdx.x >> 6;        // node phase 0..3
  const int c = (threadIdx.x & 63) << 2; // column (float4 granularity)
  float4 acc = make_float4(0.f, 0.f, 0.f, 0.f);

  const int gFirst = sb[0];
  const int gLast  = sb[cnt - 1];

  if (cnt == K1_CHUNK && gFirst == gLast) {
    // ---- fast path: single graph, fixed trip count, branch-free ----
    const float* xp = x + (size_t)start * EMBED + c;
#pragma unroll 8
    for (int i = 0; i < K1_CHUNK / 4; ++i) {
      const float4 v = *(const float4*)(xp + (size_t)(i * 4 + q) * EMBED);
      acc.x += v.x; acc.y += v.y; acc.z += v.z; acc.w += v.w;
    }
    float* p = sums + (size_t)gFirst * EMBED + c;
    atomicAdd(p + 0, acc.x); atomicAdd(p + 1, acc.y);
    atomicAdd(p + 2, acc.z); atomicAdd(p + 3, acc.w);
  } else {
    // ---- slow path: graph boundary inside chunk (or tail block) ----
    int cur = -1;
    for (int i = q; i < cnt; i += 4) {
      const int g = sb[i];  // wave-uniform broadcast
      const float4 v = *(const float4*)(x + (size_t)(start + i) * EMBED + c);
      if (g != cur) {       // wave-uniform, rare
        if (cur >= 0) {
          float* p = sums + (size_t)cur * EMBED + c;
          atomicAdd(p + 0, acc.x); atomicAdd(p + 1, acc.y);
          atomicAdd(p + 2, acc.z); atomicAdd(p + 3, acc.w);
        }
        acc = make_float4(0.f, 0.f, 0.f, 0.f);
        cur = g;
      }
      acc.x += v.x; acc.y += v.y; acc.z += v.z; acc.w += v.w;
    }
    if (cur >= 0) {
      float* p = sums + (size_t)cur * EMBED + c;
      atomicAdd(p + 0, acc.x); atomicAdd(p + 1, acc.y);
      atomicAdd(p + 2, acc.z); atomicAdd(p + 3, acc.w);
    }
  }
}

// ---------------------------------------------------------------------------
// K2: per-graph mean (count via binary search on sorted batch — no atomics),
// then out_graph = ((g @ Wv^T + bv) @ W2^T + b2). One block per graph,
// thread t owns output column t. Weight rows read as float4 (L2-hot, 512 KB).
// ---------------------------------------------------------------------------
__global__ __launch_bounds__(256) void mlp_kernel(
    const float* __restrict__ sums, const int* __restrict__ batch,
    const float* __restrict__ in_w, const float* __restrict__ in_b,
    const float* __restrict__ out_w, const float* __restrict__ out_b,
    float* __restrict__ out_graph, int nNodes) {
  const int g = blockIdx.x;
  const int t = threadIdx.x;

  int lo = 0, hi = nNodes;            // first index with batch[m] >= g
  while (lo < hi) { int m = (lo + hi) >> 1; (batch[m] <  g) ? (lo = m + 1) : (hi = m); }
  int lo2 = lo, hi2 = nNodes;         // first index with batch[m] > g
  while (lo2 < hi2) { int m = (lo2 + hi2) >> 1; (batch[m] <= g) ? (lo2 = m + 1) : (hi2 = m); }
  const float inv = 1.0f / fmaxf((float)(lo2 - lo), 1.0f);

  __shared__ float sg[EMBED];
  __shared__ float sv[EMBED];
  sg[t] = sums[(size_t)g * EMBED + t] * inv;
  __syncthreads();

  const float* Wv = in_w + 2 * EMBED * EMBED;  // value projection rows
  float acc = in_b[2 * EMBED + t];
  const float4* wrow = (const float4*)(Wv + (size_t)t * EMBED);
#pragma unroll 8
  for (int k4 = 0; k4 < EMBED / 4; ++k4) {
    const float4 w = wrow[k4];
    const int k = k4 * 4;
    acc += sg[k] * w.x + sg[k + 1] * w.y + sg[k + 2] * w.z + sg[k + 3] * w.w;
  }
  sv[t] = acc;
  __syncthreads();

  float acc2 = out_b[t];
  const float4* w2row = (const float4*)(out_w + (size_t)t * EMBED);
#pragma unroll 8
  for (int k4 = 0; k4 < EMBED / 4; ++k4) {
    const float4 w = w2row[k4];
    const int k = k4 * 4;
    acc2 += sv[k] * w.x + sv[k + 1] * w.y + sv[k + 2] * w.z + sv[k + 3] * w.w;
  }
  out_graph[(size_t)g * EMBED + t] = acc2;
}

// ---------------------------------------------------------------------------
// K3: out[n] = out_graph[batch[n]] — 204.8 MB coalesced float4 stores;
// out_graph (256 KB) is L2/L1 resident; batch load is wave-uniform.
// ---------------------------------------------------------------------------
__global__ __launch_bounds__(256) void gather_kernel(
    const float* __restrict__ out_graph, const int* __restrict__ batch,
    float4* __restrict__ out, int nNodes) {
  const int i = blockIdx.x * 256 + threadIdx.x;
  const int total = nNodes * (EMBED / 4);
  if (i >= total) return;
  const int n = i >> 6;      // node
  const int c = i & 63;      // float4 column
  const int g = batch[n];    // uniform across the 64 float4s of a node
  out[i] = ((const float4*)out_graph)[g * (EMBED / 4) + c];
}

extern "C" void kernel_launch(void* const* d_in, const int* in_sizes, int n_in,
                              void* d_out, int out_size, void* d_ws, size_t ws_size,
                              hipStream_t stream) {
  const float* x     = (const float*)d_in[0];
  const float* in_w  = (const float*)d_in[1];
  const float* in_b  = (const float*)d_in[2];
  const float* out_w = (const float*)d_in[3];
  const float* out_b = (const float*)d_in[4];
  const int*   batch = (const int*)d_in[5];
  const int nNodes = in_sizes[5];

  float* sums      = (float*)d_ws;                  // [NGRAPH][EMBED]
  float* out_graph = sums + (size_t)NGRAPH * EMBED; // [NGRAPH][EMBED]

  hipMemsetAsync(sums, 0, (size_t)NGRAPH * EMBED * sizeof(float), stream);

  const int nb1 = (nNodes + K1_CHUNK - 1) / K1_CHUNK;
  seg_sum_kernel<<<nb1, 256, 0, stream>>>(x, batch, sums, nNodes);

  mlp_kernel<<<NGRAPH, 256, 0, stream>>>(sums, batch, in_w, in_b, out_w, out_b,
                                         out_graph, nNodes);

  const int nb3 = (nNodes * (EMBED / 4) + 255) / 256;
  gather_kernel<<<nb3, 256, 0, stream>>>(out_graph, batch, (float4*)d_out, nNodes);
}

// Round 3
// 376.415 us; speedup vs baseline: 1.1127x; 1.0726x over previous
//
#include <hip/hip_runtime.h>

#define EMBED   256
#define NGRAPH  256
#define NW      8            // waves per block
#define BLOCK   (NW * 64)    // 512 threads

// ---------------------------------------------------------------------------
// Fully fused: one block per graph (batch is sorted, so graph g owns a
// contiguous node range found by binary search).
//   1) streaming segment sum (8 waves x unroll-8 float4 -> 64 KB in flight/CU)
//   2) mean + two 256x256 matvecs in-block (weights L2-hot)
//   3) broadcast row to all of the graph's nodes (coalesced 1 KB/node stores)
// No atomics, no memset, no workspace, single dispatch.
// ---------------------------------------------------------------------------
__global__ __launch_bounds__(BLOCK, 1) void fused_kernel(
    const float* __restrict__ x, const int* __restrict__ batch,
    const float* __restrict__ in_w, const float* __restrict__ in_b,
    const float* __restrict__ out_w, const float* __restrict__ out_b,
    float* __restrict__ out, int nNodes) {
  const int g = blockIdx.x;
  const int t = threadIdx.x;
  const int q  = t >> 6;   // wave id 0..7
  const int c4 = t & 63;   // float4 column 0..63

  // node range [n0, n1) for graph g
  int n0, n1;
  { int a = 0, b = nNodes;
    while (a < b) { int m = (a + b) >> 1; (batch[m] < g) ? (a = m + 1) : (b = m); }
    n0 = a; }
  { int a = n0, b = nNodes;
    while (a < b) { int m = (a + b) >> 1; (batch[m] <= g) ? (a = m + 1) : (b = m); }
    n1 = a; }
  const int cnt = n1 - n0;

  // ---- 1) segment sum: wave q handles nodes n0+q, n0+q+NW, ... ----
  const float4* xp = (const float4*)x + (size_t)n0 * (EMBED / 4) + c4;
  float4 a0 = make_float4(0.f, 0.f, 0.f, 0.f);
  float4 a1 = make_float4(0.f, 0.f, 0.f, 0.f);
  int i = q;
  for (; i + 7 * NW < cnt; i += 8 * NW) {
    float4 v0 = xp[(size_t)(i         ) * (EMBED / 4)];
    float4 v1 = xp[(size_t)(i + 1 * NW) * (EMBED / 4)];
    float4 v2 = xp[(size_t)(i + 2 * NW) * (EMBED / 4)];
    float4 v3 = xp[(size_t)(i + 3 * NW) * (EMBED / 4)];
    float4 v4 = xp[(size_t)(i + 4 * NW) * (EMBED / 4)];
    float4 v5 = xp[(size_t)(i + 5 * NW) * (EMBED / 4)];
    float4 v6 = xp[(size_t)(i + 6 * NW) * (EMBED / 4)];
    float4 v7 = xp[(size_t)(i + 7 * NW) * (EMBED / 4)];
    a0.x += v0.x + v1.x; a0.y += v0.y + v1.y; a0.z += v0.z + v1.z; a0.w += v0.w + v1.w;
    a1.x += v2.x + v3.x; a1.y += v2.y + v3.y; a1.z += v2.z + v3.z; a1.w += v2.w + v3.w;
    a0.x += v4.x + v5.x; a0.y += v4.y + v5.y; a0.z += v4.z + v5.z; a0.w += v4.w + v5.w;
    a1.x += v6.x + v7.x; a1.y += v6.y + v7.y; a1.z += v6.z + v7.z; a1.w += v6.w + v7.w;
  }
  for (; i < cnt; i += NW) {
    float4 v = xp[(size_t)i * (EMBED / 4)];
    a0.x += v.x; a0.y += v.y; a0.z += v.z; a0.w += v.w;
  }
  a0.x += a1.x; a0.y += a1.y; a0.z += a1.z; a0.w += a1.w;

  // ---- cross-wave reduce + mean ----
  __shared__ float4 red4[NW][EMBED / 4];   // layout == float [NW][EMBED]
  __shared__ float sg[EMBED];
  __shared__ float sv[EMBED];
  __shared__ float so[EMBED];
  red4[q][c4] = a0;
  __syncthreads();

  const float inv = 1.0f / fmaxf((float)cnt, 1.0f);
  if (t < EMBED) {
    const float* rf = (const float*)red4;
    float s = 0.f;
#pragma unroll
    for (int k = 0; k < NW; ++k) s += rf[k * EMBED + t];
    sg[t] = s * inv;
  }
  __syncthreads();

  // ---- 2) matvec 1: v = mean @ Wv^T + bv (thread t -> column t) ----
  if (t < EMBED) {
    float acc = in_b[2 * EMBED + t];
    const float4* wrow = (const float4*)(in_w + (size_t)(2 * EMBED + t) * EMBED);
#pragma unroll 8
    for (int k4 = 0; k4 < EMBED / 4; ++k4) {
      const float4 w = wrow[k4];
      const int k = k4 * 4;
      acc += sg[k] * w.x + sg[k + 1] * w.y + sg[k + 2] * w.z + sg[k + 3] * w.w;
    }
    sv[t] = acc;
  }
  __syncthreads();

  // ---- matvec 2: row = v @ W2^T + b2 ----
  if (t < EMBED) {
    float acc = out_b[t];
    const float4* wrow = (const float4*)(out_w + (size_t)t * EMBED);
#pragma unroll 8
    for (int k4 = 0; k4 < EMBED / 4; ++k4) {
      const float4 w = wrow[k4];
      const int k = k4 * 4;
      acc += sv[k] * w.x + sv[k + 1] * w.y + sv[k + 2] * w.z + sv[k + 3] * w.w;
    }
    so[t] = acc;
  }
  __syncthreads();

  // ---- 3) broadcast the graph row to all its nodes ----
  const float4 oval = ((const float4*)so)[c4];
  float4* op = (float4*)out + c4;
  int n = n0 + q;
  for (; n + 3 * NW < n1; n += 4 * NW) {
    op[(size_t)(n         ) * (EMBED / 4)] = oval;
    op[(size_t)(n + 1 * NW) * (EMBED / 4)] = oval;
    op[(size_t)(n + 2 * NW) * (EMBED / 4)] = oval;
    op[(size_t)(n + 3 * NW) * (EMBED / 4)] = oval;
  }
  for (; n < n1; n += NW) {
    op[(size_t)n * (EMBED / 4)] = oval;
  }
}

extern "C" void kernel_launch(void* const* d_in, const int* in_sizes, int n_in,
                              void* d_out, int out_size, void* d_ws, size_t ws_size,
                              hipStream_t stream) {
  const float* x     = (const float*)d_in[0];
  const float* in_w  = (const float*)d_in[1];
  const float* in_b  = (const float*)d_in[2];
  const float* out_w = (const float*)d_in[3];
  const float* out_b = (const float*)d_in[4];
  const int*   batch = (const int*)d_in[5];
  const int nNodes = in_sizes[5];

  fused_kernel<<<NGRAPH, BLOCK, 0, stream>>>(x, batch, in_w, in_b, out_w, out_b,
                                             (float*)d_out, nNodes);
}